// Round 1
// baseline (2293.224 us; speedup 1.0000x reference)
//
#include <hip/hip_runtime.h>
#include <math.h>

// ---------------- compile-time problem constants ----------------
#define TOTE 5400000   // total edges
#define TOTN 234000    // total node rows (all types concatenated)
#define TOTC 514000    // total dst slots over 14 edge types
#define HID  128

// bucketed CSR build
#define NBUK 251        // coarse dst-range buckets over all 14 edge types
#define NBLK_FILL 512   // blocks in bfill_k
#define CAPCH 470000    // chunk pool capacity: <= TOTE/16 full + NBLK_FILL*NBUK partial = 466012

// ws carve (~234.6 MB, proven-safe ceiling 245.8 MB):
//   h_bf (59.9MB) + w_bf (3.05MB) + slot (131.6MB) + cnt/cursor/invdeg (6.2MB)
//   + chunk pool (30.1MB) + chunkTag (1.9MB) + chunkIdx (1.9MB) + ctrl (6KB)
// d_out scratch: col (21.6MB), overwritten by the head GEMM at the end.

typedef __attribute__((ext_vector_type(8))) short short8;
typedef __attribute__((ext_vector_type(8))) __bf16 bf16x8;
typedef __attribute__((ext_vector_type(4))) float floatx4;

__constant__ int c_EPRE[15]   = {0,1000000,2000000,2500000,3000000,3200000,3400000,3600000,3800000,3900000,4000000,4300000,4600000,5000000,5400000};
__constant__ int c_ECNT[14]   = {1000000,1000000,500000,500000,200000,200000,200000,200000,100000,100000,300000,300000,400000,400000};
__constant__ int c_CNTOFF[14] = {0,40000,140000,143000,183000,203000,243000,263000,303000,311000,351000,411000,451000,454000};
__constant__ int c_CNTN[14]   = {40000,100000,3000,40000,20000,40000,20000,40000,8000,40000,60000,40000,3000,60000};
__constant__ int c_SRCOFF[14] = {0,100000,100000,140000,100000,143000,100000,143000,100000,163000,100000,171000,171000,231000};
__constant__ int c_NODEPRE[8] = {0,100000,140000,143000,163000,171000,231000,234000};
__constant__ float c_INVND[7] = {1.0f, 1.0f/6.0f, 1.0f, 0.5f, 1.0f, 0.5f, 1.0f};
// slot ranges feeding each dst node type (for update_k)
__constant__ int c_UPD_NS[7]      = {1,6,1,2,1,2,1};
__constant__ int c_UPD_BASE[7][6] = {
    {40000,0,0,0,0,0},
    {0,143000,203000,263000,311000,411000},
    {140000,0,0,0,0,0},
    {183000,243000,0,0,0,0},
    {303000,0,0,0,0,0},
    {351000,454000,0,0,0,0},
    {451000,0,0,0,0,0}};
// bucket tables: per-type dst shift and bucket-id base (prefix of ceil(CNTN/2^sh))
__constant__ int c_BSH[14]   = {10,11,7,11,11,12,11,12,11,12,12,12,7,12};
__constant__ int c_BBASE[15] = {0,40,89,113,133,143,153,163,173,177,187,202,212,236,251};

static __device__ __forceinline__ unsigned short f2bf(float f) {
    unsigned u = __float_as_uint(f);
    u = u + 0x7FFFu + ((u >> 16) & 1u);
    return (unsigned short)(u >> 16);
}
static __device__ __forceinline__ float bf2f(unsigned short s) {
    return __uint_as_float(((unsigned)s) << 16);
}
static __device__ __forceinline__ unsigned short f2h(float f) {
    _Float16 h = (_Float16)f;
    return __builtin_bit_cast(unsigned short, h);
}
static __device__ __forceinline__ float h2f(unsigned short s) {
    _Float16 h = __builtin_bit_cast(_Float16, s);
    return (float)h;
}

struct EdgeArgs { const int* ei[14]; };

// ---------------- CSR build, chunked bucket sort ----------------
// Record: (slot_local:12 | src_global:18), < 2^30. Sentinel pad = 0xFFFFFFFF (>>30 != 0).

// Stage 1: block-level multisplit. Each block owns a contiguous edge range; LDS queues of
// 16 records per bucket; full queues flush as one aligned 64B chunk written by ONE thread
// (full-line write, no partial-line XCD amplification). Per-bucket edge counts accumulate
// from flush atomics (replaces count_k).
__global__ __launch_bounds__(256) void bfill_k(EdgeArgs a, unsigned* __restrict__ pool,
        int* __restrict__ chunkTag, int* __restrict__ nchunks,
        int* __restrict__ bktCnt, int* __restrict__ bktChunkCnt) {
    __shared__ unsigned q[NBUK * 16];
    __shared__ int qn[NBUK];
    int t = threadIdx.x;
    for (int i = t; i < NBUK; i += 256) qn[i] = 0;
    __syncthreads();
    const int per = (TOTE + NBLK_FILL - 1) / NBLK_FILL;
    int s = blockIdx.x * per;
    int eEnd = min(s + per, TOTE);
    for (int base = s; base < eEnd; base += 256) {
        int g = base + t;
        bool pend = (g < eEnd);
        unsigned rec = 0; int bkt = 0;
        if (pend) {
            int e = 0;
            while (g >= c_EPRE[e + 1]) e++;
            int k = g - c_EPRE[e];
            int src = a.ei[e][k];
            int dst = a.ei[e][c_ECNT[e] + k];
            int sh = c_BSH[e];
            rec = ((unsigned)(dst & ((1 << sh) - 1)) << 18) | (unsigned)(c_SRCOFF[e] + src);
            bkt = c_BBASE[e] + (dst >> sh);
        }
        while (true) {
            if (pend) {
                int p = atomicAdd(&qn[bkt], 1);
                if (p < 16) { q[bkt * 16 + p] = rec; pend = false; }
            }
            __syncthreads();
            if (t < NBUK) {
                int n = qn[t];
                if (n >= 16) {
                    int cid = atomicAdd(nchunks, 1);
                    chunkTag[cid] = t;
                    atomicAdd(&bktCnt[t], 16);
                    atomicAdd(&bktChunkCnt[t], 1);
                    uint4* d4 = (uint4*)(pool + (size_t)cid * 16);
                    const uint4* s4 = (const uint4*)&q[t * 16];
                    d4[0] = s4[0]; d4[1] = s4[1]; d4[2] = s4[2]; d4[3] = s4[3];
                    qn[t] = 0;     // overflow appenders retry into the fresh queue
                }
            }
            if (!__syncthreads_or(pend ? 1 : 0)) break;
        }
    }
    // drain partial queues (padded with sentinel)
    __syncthreads();
    if (t < NBUK) {
        int n = qn[t];
        if (n > 0) {
            int cid = atomicAdd(nchunks, 1);
            chunkTag[cid] = t;
            atomicAdd(&bktCnt[t], n);
            atomicAdd(&bktChunkCnt[t], 1);
            for (int i = n; i < 16; i++) q[t * 16 + i] = 0xFFFFFFFFu;
            uint4* d4 = (uint4*)(pool + (size_t)cid * 16);
            const uint4* s4 = (const uint4*)&q[t * 16];
            d4[0] = s4[0]; d4[1] = s4[1]; d4[2] = s4[2]; d4[3] = s4[3];
        }
    }
}

// Stage 2: two tiny exclusive scans. Block 0: bucket edge counts -> bucket edge bases
// (these ARE the CSR col bases, since bucket order == slot order). Block 1: chunk counts.
__global__ __launch_bounds__(256) void scans_k(const int* __restrict__ bktCnt,
        const int* __restrict__ bktChunkCnt,
        int* __restrict__ bktEdgeBase, int* __restrict__ bktChunkBase) {
    const int* in = blockIdx.x ? bktChunkCnt : bktCnt;
    int* out      = blockIdx.x ? bktChunkBase : bktEdgeBase;
    int t = threadIdx.x;
    int v = (t < NBUK) ? in[t] : 0;
    int lane = t & 63, w = t >> 6;
    __shared__ int wt[4];
    int incl = v;
    #pragma unroll
    for (int d = 1; d < 64; d <<= 1) { int o = __shfl_up(incl, d); if (lane >= d) incl += o; }
    if (lane == 63) wt[w] = incl;
    __syncthreads();
    int wb = 0;
    for (int i = 0; i < w; i++) wb += wt[i];
    int excl = incl - v + wb;
    if (t < NBUK) out[t] = excl;
    if (t == NBUK - 1) out[NBUK] = excl + v;
}

// Stage 3: group chunk ids by bucket.
__global__ __launch_bounds__(256) void cscatter_k(const int* __restrict__ chunkTag,
        const int* __restrict__ nchunks, const int* __restrict__ bktChunkBase,
        int* __restrict__ bktChunkCur, int* __restrict__ chunkIdx) {
    int cid = blockIdx.x * 256 + threadIdx.x;
    if (cid >= *nchunks) return;
    int b = chunkTag[cid];
    int p = atomicAdd(&bktChunkCur[b], 1);
    chunkIdx[bktChunkBase[b] + p] = cid;
}

// Stage 4: one block per bucket. LDS histogram+scan over the bucket's <=4096 slots;
// dense writes of cnt/cursor(end)/invdeg; scatter src ids into the bucket's contiguous
// col range (~<=120KB -> stays in ONE XCD's L2 -> fully merged writebacks).
__global__ __launch_bounds__(256) void csrfill_k(
        const unsigned* __restrict__ pool, const int* __restrict__ chunkIdx,
        const int* __restrict__ bktChunkCnt, const int* __restrict__ bktChunkBase,
        const int* __restrict__ bktEdgeBase,
        int* __restrict__ cnt, int* __restrict__ cursor, float* __restrict__ invdeg,
        int* __restrict__ col) {
    __shared__ int hist[4096];
    __shared__ int cur[4096];
    __shared__ int wtot[4];
    __shared__ int wbase[4];
    int b = blockIdx.x;
    int t = threadIdx.x;
    int e = 0;
    while (b >= c_BBASE[e + 1]) e++;
    int lb = b - c_BBASE[e];
    int sh = c_BSH[e];
    int s0t = lb << sh;
    int span = min(1 << sh, c_CNTN[e] - s0t);
    int gs0 = c_CNTOFF[e] + s0t;
    int ebase = bktEdgeBase[b];
    int nch = bktChunkCnt[b];
    int cb = bktChunkBase[b];

    for (int i = t; i < span; i += 256) hist[i] = 0;
    __syncthreads();
    // phase 1: slot histogram
    int tot16 = nch * 16;
    for (int idx = t; idx < tot16; idx += 256) {
        int cid = chunkIdx[cb + (idx >> 4)];
        unsigned rec = pool[(size_t)cid * 16 + (idx & 15)];
        if ((rec >> 30) == 0) atomicAdd(&hist[rec >> 18], 1);
    }
    __syncthreads();
    // phase 2: block exclusive scan over span (16 elems/thread)
    int base = t * 16;
    int loc = 0;
    int lv[16];
    #pragma unroll
    for (int i = 0; i < 16; i++) {
        int ii = base + i;
        int v = (ii < span) ? hist[ii] : 0;
        lv[i] = loc;
        loc += v;
    }
    int lane = t & 63, w = t >> 6;
    int incl = loc;
    #pragma unroll
    for (int d = 1; d < 64; d <<= 1) { int o = __shfl_up(incl, d); if (lane >= d) incl += o; }
    if (lane == 63) wtot[w] = incl;
    __syncthreads();
    if (t == 0) { int s = 0; for (int i = 0; i < 4; i++) { wbase[i] = s; s += wtot[i]; } }
    __syncthreads();
    int texcl = incl - loc + wbase[w];
    #pragma unroll
    for (int i = 0; i < 16; i++) {
        int ii = base + i;
        if (ii < span) cur[ii] = texcl + lv[i];
    }
    __syncthreads();
    // per-slot CSR outputs (dense, coalesced)
    for (int i = t; i < span; i += 256) {
        int c = hist[i];
        cnt[gs0 + i] = c;
        cursor[gs0 + i] = ebase + cur[i] + c;     // end semantics (matches agg_k)
        invdeg[gs0 + i] = 1.0f / fmaxf((float)c, 1.0f);
    }
    __syncthreads();
    // phase 3: scatter src ids within this bucket's contiguous col range
    for (int idx = t; idx < tot16; idx += 256) {
        int cid = chunkIdx[cb + (idx >> 4)];
        unsigned rec = pool[(size_t)cid * 16 + (idx & 15)];
        if ((rec >> 30) == 0) {
            int p = atomicAdd(&cur[rec >> 18], 1);
            col[ebase + p] = (int)(rec & 0x3FFFFu);
        }
    }
}

// ---------------- conversions ----------------
struct XArgs { const float* x[7]; };
__global__ __launch_bounds__(256) void convx_k(XArgs a, unsigned short* __restrict__ hbf) {
    int i4 = blockIdx.x * 256 + threadIdx.x;
    if (i4 >= TOTN * 32) return;           // float4 index
    int idx = i4 * 4;
    int t = 0;
    while (idx >= c_NODEPRE[t + 1] * 128) t++;
    float4 v = *(const float4*)&a.x[t][idx - c_NODEPRE[t] * 128];
    uint2 p;
    p.x = (unsigned)f2bf(v.x) | ((unsigned)f2bf(v.y) << 16);
    p.y = (unsigned)f2bf(v.z) | ((unsigned)f2bf(v.w) << 16);
    *(uint2*)&hbf[idx] = p;
}

// weight slots: 0-6 Wp, 7-48 Wl(l*14+e), 49-90 Wr, 91 Wu, 92 Wv  (93 * 16384 elements)
struct WArgs { const float* Wp; const float* Wl; const float* Wr; const float* Wu; const float* Wv; };
__global__ __launch_bounds__(256) void convw_k(WArgs a, unsigned short* __restrict__ wbf) {
    int i4 = blockIdx.x * 256 + threadIdx.x;
    if (i4 >= 93 * 4096) return;
    int idx = i4 * 4;
    int m = idx >> 14;
    int i = idx & 16383;
    const float* src;
    if (m < 7)       src = a.Wp + (size_t)m * 16384;
    else if (m < 49) src = a.Wl + (size_t)(m - 7) * 16384;
    else if (m < 91) src = a.Wr + (size_t)(m - 49) * 16384;
    else if (m == 91) src = a.Wu;
    else              src = a.Wv;
    float4 v = *(const float4*)&src[i];
    uint2 p;
    p.x = (unsigned)f2bf(v.x) | ((unsigned)f2bf(v.y) << 16);
    p.y = (unsigned)f2bf(v.z) | ((unsigned)f2bf(v.w) << 16);
    *(uint2*)&wbf[idx] = p;
}

// ---------------- aggregation: one wave per slot, quarter-wave per neighbor ----------------
#define ACC8(u) do { \
    v[0] += __uint_as_float((u).x << 16); v[1] += __uint_as_float((u).x & 0xFFFF0000u); \
    v[2] += __uint_as_float((u).y << 16); v[3] += __uint_as_float((u).y & 0xFFFF0000u); \
    v[4] += __uint_as_float((u).z << 16); v[5] += __uint_as_float((u).z & 0xFFFF0000u); \
    v[6] += __uint_as_float((u).w << 16); v[7] += __uint_as_float((u).w & 0xFFFF0000u); } while (0)

__global__ __launch_bounds__(256) void agg_k(
        const int* __restrict__ cnt, const int* __restrict__ cursor,
        const float* __restrict__ inv_deg, const int* __restrict__ col,
        const unsigned short* __restrict__ hbf, unsigned short* __restrict__ slotb) {
    int row = blockIdx.x * 4 + (threadIdx.x >> 6);
    if (row >= TOTC) return;
    int lane = threadIdx.x & 63;
    int q = lane >> 4, li = lane & 15;
    int nn = cnt[row];
    int rs = cursor[row] - nn;           // cursor==end
    const int* cp = col + rs;
    float v[8];
    #pragma unroll
    for (int i = 0; i < 8; i++) v[i] = 0.f;
    int j = 0;
    for (; j + 8 <= nn; j += 8) {
        int c0 = cp[j + q] << 7;
        int c1 = cp[j + 4 + q] << 7;
        uint4 u0 = *(const uint4*)&hbf[c0 + li * 8];
        uint4 u1 = *(const uint4*)&hbf[c1 + li * 8];
        ACC8(u0);
        ACC8(u1);
    }
    for (; j < nn; j += 4) {
        if (j + q < nn) {
            int c = cp[j + q] << 7;
            uint4 u = *(const uint4*)&hbf[c + li * 8];
            ACC8(u);
        }
    }
    float inv = inv_deg[row];
    #pragma unroll
    for (int i = 0; i < 8; i++) {
        v[i] += __shfl_xor(v[i], 16);
        v[i] += __shfl_xor(v[i], 32);
        v[i] *= inv;
    }
    if (q == 0) {
        uint4 o;
        o.x = (unsigned)f2bf(v[0]) | ((unsigned)f2bf(v[1]) << 16);
        o.y = (unsigned)f2bf(v[2]) | ((unsigned)f2bf(v[3]) << 16);
        o.z = (unsigned)f2bf(v[4]) | ((unsigned)f2bf(v[5]) << 16);
        o.w = (unsigned)f2bf(v[6]) | ((unsigned)f2bf(v[7]) << 16);
        *(uint4*)&slotb[(size_t)row * HID + li * 8] = o;
    }
}

// ---------------- MFMA GEMM: out = A1@W1^T (+ A2@W2^T) + bias [, l2norm] ----------------
struct GemmArgs {
    int blockPrefix[15];
    const unsigned short* A1[14]; const unsigned short* A2[14];
    const unsigned short* W1[14]; const unsigned short* W2[14];
    const float* bias[14]; void* out[14];
    int rows[14];
};

template<int MODE, bool TWO>
__global__ __launch_bounds__(256) void gemm_k(GemmArgs g) {
    __shared__ short As[64 * 40];
    __shared__ short Ws[128 * 40];
    int b = blockIdx.x;
    int s = 0;
    while (b >= g.blockPrefix[s + 1]) s++;
    int rows = g.rows[s];
    int row0 = (b - g.blockPrefix[s]) * 64;
    int t = threadIdx.x;
    int w = t >> 6, lane = t & 63;
    int q = lane >> 4, m15 = lane & 15;

    floatx4 acc[8];
    #pragma unroll
    for (int bb = 0; bb < 8; bb++) acc[bb] = (floatx4){0.f, 0.f, 0.f, 0.f};

    const int MM = TWO ? 2 : 1;
    for (int mm = 0; mm < MM; mm++) {
        const uint4* A4 = (const uint4*)(mm ? g.A2[s] : g.A1[s]);
        const uint4* W4 = (const uint4*)(mm ? g.W2[s] : g.W1[s]);
        for (int k0 = 0; k0 < 128; k0 += 32) {
            __syncthreads();
            {   // A tile
                int row = t >> 2, kc = t & 3;
                uint4 v = make_uint4(0u, 0u, 0u, 0u);
                if (row0 + row < rows) v = A4[(size_t)(row0 + row) * 16 + (k0 >> 3) + kc];
                *(uint4*)&As[row * 40 + kc * 8] = v;
            }
            #pragma unroll
            for (int i = 0; i < 2; i++) {   // W tile
                int idx = t + i * 256;
                int c = idx >> 2, kc = idx & 3;
                uint4 v = W4[(size_t)c * 16 + (k0 >> 3) + kc];
                *(uint4*)&Ws[c * 40 + kc * 8] = v;
            }
            __syncthreads();
            bf16x8 af = __builtin_bit_cast(bf16x8, *(const short8*)&As[(w * 16 + m15) * 40 + q * 8]);
            #pragma unroll
            for (int bb = 0; bb < 8; bb++) {
                bf16x8 bf = __builtin_bit_cast(bf16x8, *(const short8*)&Ws[(bb * 16 + m15) * 40 + q * 8]);
                acc[bb] = __builtin_amdgcn_mfma_f32_16x16x32_bf16(af, bf, acc[bb], 0, 0, 0);
            }
        }
    }

    const float* bias = g.bias[s];
    #pragma unroll
    for (int bb = 0; bb < 8; bb++) {
        float bv = bias[bb * 16 + m15];
        #pragma unroll
        for (int reg = 0; reg < 4; reg++) acc[bb][reg] += bv;
    }
    if (MODE != 0) {
        #pragma unroll
        for (int reg = 0; reg < 4; reg++) {
            float ss = 0.f;
            #pragma unroll
            for (int bb = 0; bb < 8; bb++) ss += acc[bb][reg] * acc[bb][reg];
            ss += __shfl_xor(ss, 1);
            ss += __shfl_xor(ss, 2);
            ss += __shfl_xor(ss, 4);
            ss += __shfl_xor(ss, 8);
            float sc = 1.0f / fmaxf(sqrtf(ss), 1e-12f);
            #pragma unroll
            for (int bb = 0; bb < 8; bb++) acc[bb][reg] *= sc;
        }
    }
    int rbase = row0 + w * 16 + q * 4;
    if (MODE == 3) {
        float* out = (float*)g.out[s];
        #pragma unroll
        for (int reg = 0; reg < 4; reg++) {
            int r = rbase + reg;
            if (r < rows) {
                float* o = out + (size_t)r * HID;
                #pragma unroll
                for (int bb = 0; bb < 8; bb++) o[bb * 16 + m15] = acc[bb][reg];
            }
        }
    } else {
        unsigned short* out = (unsigned short*)g.out[s];
        #pragma unroll
        for (int reg = 0; reg < 4; reg++) {
            int r = rbase + reg;
            if (r < rows) {
                unsigned short* o = out + (size_t)r * HID;
                #pragma unroll
                for (int bb = 0; bb < 8; bb++)
                    o[bb * 16 + m15] = (MODE == 0) ? f2bf(acc[bb][reg]) : f2h(acc[bb][reg]);
            }
        }
    }
}

// ---------------- per-layer update ----------------
__global__ __launch_bounds__(256) void update_k(unsigned short* __restrict__ hbf,
                                                const unsigned short* __restrict__ slotb,
                                                const float* __restrict__ ln_g, const float* __restrict__ ln_b, int l) {
    int row = blockIdx.x * 4 + (threadIdx.x >> 6);
    if (row >= TOTN) return;
    int lane = threadIdx.x & 63;
    int t = 0;
    while (row >= c_NODEPRE[t + 1]) t++;
    int r = row - c_NODEPRE[t];
    int ns = c_UPD_NS[t];
    float s0 = 0.f, s1 = 0.f;
    for (int s = 0; s < ns; s++) {
        const unsigned short* sp = slotb + (size_t)(c_UPD_BASE[t][s] + r) * HID;
        s0 += h2f(sp[lane]);
        s1 += h2f(sp[lane + 64]);
    }
    float invnd = c_INVND[t];
    const float* gg = ln_g + ((size_t)l * 7 + t) * HID;
    const float* bb = ln_b + ((size_t)l * 7 + t) * HID;
    unsigned short* hp = hbf + (size_t)row * HID;
    float x0 = s0 * invnd + bf2f(hp[lane]);
    float x1 = s1 * invnd + bf2f(hp[lane + 64]);
    float s = x0 + x1;
    s += __shfl_xor(s, 1);  s += __shfl_xor(s, 2);  s += __shfl_xor(s, 4);
    s += __shfl_xor(s, 8);  s += __shfl_xor(s, 16); s += __shfl_xor(s, 32);
    float mean = s * (1.0f / 128.0f);
    float d0 = x0 - mean, d1 = x1 - mean;
    float vs = d0 * d0 + d1 * d1;
    vs += __shfl_xor(vs, 1);  vs += __shfl_xor(vs, 2);  vs += __shfl_xor(vs, 4);
    vs += __shfl_xor(vs, 8);  vs += __shfl_xor(vs, 16); vs += __shfl_xor(vs, 32);
    float rstd = rsqrtf(vs * (1.0f / 128.0f) + 1e-5f);
    float y0 = d0 * rstd * gg[lane]      + bb[lane];
    float y1 = d1 * rstd * gg[lane + 64] + bb[lane + 64];
    hp[lane]      = f2bf(fmaxf(y0, 0.f));
    hp[lane + 64] = f2bf(fmaxf(y1, 0.f));
}

// ---------------- host ----------------
extern "C" void kernel_launch(void* const* d_in, const int* in_sizes, int n_in,
                              void* d_out, int out_size, void* d_ws, size_t ws_size,
                              hipStream_t stream) {
    (void)in_sizes; (void)n_in; (void)out_size; (void)ws_size;
    const float* Wp   = (const float*)d_in[21];
    const float* bp   = (const float*)d_in[22];
    const float* Wl   = (const float*)d_in[23];
    const float* bl   = (const float*)d_in[24];
    const float* Wr   = (const float*)d_in[25];
    const float* ln_g = (const float*)d_in[26];
    const float* ln_b = (const float*)d_in[27];
    const float* Wu   = (const float*)d_in[28];
    const float* bu   = (const float*)d_in[29];
    const float* Wv   = (const float*)d_in[30];
    const float* bv   = (const float*)d_in[31];
    float* out = (float*)d_out;

    // d_ws carve (~234.6 MB)
    unsigned short* h_bf   = (unsigned short*)d_ws;                  // TOTN*128 bf16
    unsigned short* w_bf   = h_bf + (size_t)TOTN * HID;              // 93*16384 bf16
    unsigned short* slotb  = w_bf + (size_t)93 * 16384;              // TOTC*128 bf16/f16
    int*            cnt    = (int*)(slotb + (size_t)TOTC * HID);     // TOTC
    int*            cursor = cnt + TOTC;                             // TOTC
    float*          invdeg = (float*)(cursor + TOTC);                // TOTC
    unsigned*       pool   = (unsigned*)(invdeg + TOTC);             // CAPCH * 16 (64B chunks)
    int*            chunkTag = (int*)(pool + (size_t)CAPCH * 16);    // CAPCH
    int*            chunkIdx = chunkTag + CAPCH;                     // CAPCH
    int*            ctrl     = chunkIdx + CAPCH;                     // control block
    int* bktCnt       = ctrl;                 // NBUK
    int* bktChunkCnt  = ctrl + NBUK;          // NBUK
    int* bktChunkCur  = ctrl + 2 * NBUK;      // NBUK
    int* nchunks      = ctrl + 3 * NBUK;      // 1
    int* bktEdgeBase  = ctrl + 3 * NBUK + 1;  // NBUK+1
    int* bktChunkBase = bktEdgeBase + NBUK + 1; // NBUK+1

    // d_out scratch (overwritten by final head GEMM)
    int* col = (int*)d_out;                                          // TOTE ints

    static const int CNTOFF[14] = {0,40000,140000,143000,183000,203000,243000,263000,303000,311000,351000,411000,451000,454000};
    static const int CNTN[14]   = {40000,100000,3000,40000,20000,40000,20000,40000,8000,40000,60000,40000,3000,60000};
    static const int DSTOFF[14] = {100000,0,140000,100000,143000,100000,143000,100000,163000,100000,171000,100000,231000,171000};
    static const int NODEPRE[8] = {0,100000,140000,143000,163000,171000,231000,234000};
    static const int NT[7]      = {100000,40000,3000,20000,8000,60000,3000};

    EdgeArgs ea;
    for (int e = 0; e < 14; e++) ea.ei[e] = (const int*)d_in[7 + e];

    // CSR build: multisplit -> scans -> chunk grouping -> per-bucket fill
    hipMemsetAsync(ctrl, 0, (3 * NBUK + 1) * sizeof(int), stream);
    bfill_k<<<NBLK_FILL, 256, 0, stream>>>(ea, pool, chunkTag, nchunks, bktCnt, bktChunkCnt);
    scans_k<<<2, 256, 0, stream>>>(bktCnt, bktChunkCnt, bktEdgeBase, bktChunkBase);
    cscatter_k<<<(CAPCH + 255) / 256, 256, 0, stream>>>(chunkTag, nchunks, bktChunkBase, bktChunkCur, chunkIdx);
    csrfill_k<<<NBUK, 256, 0, stream>>>(pool, chunkIdx, bktChunkCnt, bktChunkBase, bktEdgeBase,
                                        cnt, cursor, invdeg, col);

    {   // conversions
        XArgs xa;
        for (int t = 0; t < 7; t++) xa.x[t] = (const float*)d_in[t];
        convx_k<<<(TOTN * 32 + 255) / 256, 256, 0, stream>>>(xa, h_bf);
        WArgs wa = {Wp, Wl, Wr, Wu, Wv};
        convw_k<<<(93 * 4096 + 255) / 256, 256, 0, stream>>>(wa, w_bf);
    }

    // input projection (in-place bf16): h_bf[t] = x_bf[t] @ Wp[t]^T + bp[t]
    {
        GemmArgs ga;
        int pre = 0; ga.blockPrefix[0] = 0;
        for (int t = 0; t < 7; t++) {
            ga.A1[t] = h_bf + (size_t)NODEPRE[t] * HID;
            ga.A2[t] = nullptr;
            ga.W1[t] = w_bf + (size_t)t * 16384;
            ga.W2[t] = nullptr;
            ga.bias[t] = bp + (size_t)t * HID;
            ga.out[t] = h_bf + (size_t)NODEPRE[t] * HID;
            ga.rows[t] = NT[t];
            pre += (NT[t] + 63) / 64;
            ga.blockPrefix[t + 1] = pre;
        }
        for (int s = 7; s < 14; s++) { ga.blockPrefix[s + 1] = pre; ga.rows[s] = 0; }
        gemm_k<0, false><<<pre, 256, 0, stream>>>(ga);
    }

    // layers: one agg + one gemm + one update dispatch each
    int ggrid;
    GemmArgs gl;
    {
        int pre = 0; gl.blockPrefix[0] = 0;
        for (int e = 0; e < 14; e++) {
            gl.rows[e] = CNTN[e];
            pre += (CNTN[e] + 63) / 64;
            gl.blockPrefix[e + 1] = pre;
        }
        ggrid = pre;
    }
    for (int l = 0; l < 3; l++) {
        agg_k<<<(TOTC + 3) / 4, 256, 0, stream>>>(cnt, cursor, invdeg, col, h_bf, slotb);
        for (int e = 0; e < 14; e++) {
            gl.A1[e]   = slotb + (size_t)CNTOFF[e] * HID;
            gl.A2[e]   = h_bf + (size_t)DSTOFF[e] * HID;
            gl.W1[e]   = w_bf + (size_t)(7  + l * 14 + e) * 16384;
            gl.W2[e]   = w_bf + (size_t)(49 + l * 14 + e) * 16384;
            gl.bias[e] = bl + ((size_t)l * 14 + e) * HID;
            gl.out[e]  = slotb + (size_t)CNTOFF[e] * HID;   // in-place: bf16 in, f16 out
        }
        gemm_k<1, true><<<ggrid, 256, 0, stream>>>(gl);
        update_k<<<(TOTN + 3) / 4, 256, 0, stream>>>(h_bf, slotb, ln_g, ln_b, l);
    }

    // heads: l2norm(h @ W^T + b) -> fp32 out (overwrites the col scratch in d_out)
    {
        GemmArgs ga;
        ga.blockPrefix[0] = 0;
        ga.A1[0] = h_bf;                        ga.A2[0] = nullptr;
        ga.W1[0] = w_bf + (size_t)91 * 16384;   ga.W2[0] = nullptr;
        ga.bias[0] = bu;                        ga.out[0] = out;
        ga.rows[0] = 100000;
        ga.blockPrefix[1] = (100000 + 63) / 64;
        ga.A1[1] = h_bf + (size_t)100000 * HID; ga.A2[1] = nullptr;
        ga.W1[1] = w_bf + (size_t)92 * 16384;   ga.W2[1] = nullptr;
        ga.bias[1] = bv;                        ga.out[1] = out + (size_t)100000 * HID;
        ga.rows[1] = 40000;
        int tot = ga.blockPrefix[1] + (40000 + 63) / 64;
        for (int s = 2; s < 14; s++) { ga.blockPrefix[s + 1] = tot; ga.rows[s] = 0; }
        ga.blockPrefix[2] = tot;
        gemm_k<3, false><<<tot, 256, 0, stream>>>(ga);
    }
}

// Round 2
// 1613.151 us; speedup vs baseline: 1.4216x; 1.4216x over previous
//
#include <hip/hip_runtime.h>
#include <math.h>

// ---------------- compile-time problem constants ----------------
#define TOTE 5400000   // total edges
#define TOTN 234000    // total node rows (all types concatenated)
#define TOTC 514000    // total dst slots over 14 edge types
#define HID  128

// bucketed CSR build (two-pass stable binning, no global atomics)
#define NBUK 499        // coarse dst-range buckets over all 14 edge types (span <= 2048 slots)
#define NBLK 1024       // blocks in hist_k / scatter_k (NBLK == 256*4 for scan_blk_k)

// ws carve (~224.4 MB, proven-safe ceiling 245.8 MB):
//   h_bf (59.9MB) + w_bf (3.05MB) + slot (131.6MB) + cnt/cursor/invdeg (6.2MB)
//   + record pool (21.6MB) + blkHist (2.04MB) + ctrl (4KB)
// d_out scratch: col (21.6MB), overwritten by the head GEMM at the end.

typedef __attribute__((ext_vector_type(8))) short short8;
typedef __attribute__((ext_vector_type(8))) __bf16 bf16x8;
typedef __attribute__((ext_vector_type(4))) float floatx4;

__constant__ int c_EPRE[15]   = {0,1000000,2000000,2500000,3000000,3200000,3400000,3600000,3800000,3900000,4000000,4300000,4600000,5000000,5400000};
__constant__ int c_ECNT[14]   = {1000000,1000000,500000,500000,200000,200000,200000,200000,100000,100000,300000,300000,400000,400000};
__constant__ int c_CNTOFF[14] = {0,40000,140000,143000,183000,203000,243000,263000,303000,311000,351000,411000,451000,454000};
__constant__ int c_CNTN[14]   = {40000,100000,3000,40000,20000,40000,20000,40000,8000,40000,60000,40000,3000,60000};
__constant__ int c_SRCOFF[14] = {0,100000,100000,140000,100000,143000,100000,143000,100000,163000,100000,171000,171000,231000};
__constant__ int c_NODEPRE[8] = {0,100000,140000,143000,163000,171000,231000,234000};
__constant__ float c_INVND[7] = {1.0f, 1.0f/6.0f, 1.0f, 0.5f, 1.0f, 0.5f, 1.0f};
// slot ranges feeding each dst node type (for update_k)
__constant__ int c_UPD_NS[7]      = {1,6,1,2,1,2,1};
__constant__ int c_UPD_BASE[7][6] = {
    {40000,0,0,0,0,0},
    {0,143000,203000,263000,311000,411000},
    {140000,0,0,0,0,0},
    {183000,243000,0,0,0,0},
    {303000,0,0,0,0,0},
    {351000,454000,0,0,0,0},
    {451000,0,0,0,0,0}};
// bucket tables: per-type dst shift and bucket-id base (prefix of ceil(CNTN/2^sh))
__constant__ int c_BSH[14]   = {9,10,6,10,10,11,10,11,10,11,11,11,6,11};
__constant__ int c_BBASE[15] = {0,79,177,224,264,284,304,324,344,352,372,402,422,469,499};

static __device__ __forceinline__ unsigned short f2bf(float f) {
    unsigned u = __float_as_uint(f);
    u = u + 0x7FFFu + ((u >> 16) & 1u);
    return (unsigned short)(u >> 16);
}
static __device__ __forceinline__ float bf2f(unsigned short s) {
    return __uint_as_float(((unsigned)s) << 16);
}
static __device__ __forceinline__ unsigned short f2h(float f) {
    _Float16 h = (_Float16)f;
    return __builtin_bit_cast(unsigned short, h);
}
static __device__ __forceinline__ float h2f(unsigned short s) {
    _Float16 h = __builtin_bit_cast(_Float16, s);
    return (float)h;
}

struct EdgeArgs { const int* ei[14]; };

// ---------------- CSR build: stable two-pass binning ----------------
// Record: (slot_local:11 | src_global:18), < 2^29.

// Pass 1: per-block bucket histogram (LDS atomics only), written bucket-major.
__global__ __launch_bounds__(256) void hist_k(EdgeArgs a, int* __restrict__ blkHist) {
    __shared__ int h[NBUK];
    int t = threadIdx.x;
    for (int i = t; i < NBUK; i += 256) h[i] = 0;
    __syncthreads();
    const int per = (TOTE + NBLK - 1) / NBLK;
    int s = blockIdx.x * per;
    int eEnd = min(s + per, TOTE);
    for (int g = s + t; g < eEnd; g += 256) {
        int e = 0;
        while (g >= c_EPRE[e + 1]) e++;
        int k = g - c_EPRE[e];
        int dst = a.ei[e][c_ECNT[e] + k];
        atomicAdd(&h[c_BBASE[e] + (dst >> c_BSH[e])], 1);
    }
    __syncthreads();
    for (int i = t; i < NBUK; i += 256) blkHist[(size_t)i * NBLK + blockIdx.x] = h[i];
}

// Pass 2a: per-bucket exclusive scan over NBLK block counts (in-place), total -> bktCnt.
__global__ __launch_bounds__(256) void scan_blk_k(int* __restrict__ blkHist, int* __restrict__ bktCnt) {
    int b = blockIdx.x;
    int* p = blkHist + (size_t)b * NBLK;
    int t = threadIdx.x;
    int4 v = *(int4*)&p[t * 4];
    int s = v.x + v.y + v.z + v.w;
    int lane = t & 63, w = t >> 6;
    __shared__ int wt[4];
    int incl = s;
    #pragma unroll
    for (int d = 1; d < 64; d <<= 1) { int o = __shfl_up(incl, d); if (lane >= d) incl += o; }
    if (lane == 63) wt[w] = incl;
    __syncthreads();
    int wb = 0;
    for (int i = 0; i < w; i++) wb += wt[i];
    int excl = incl - s + wb;
    int4 o;
    o.x = excl; o.y = excl + v.x; o.z = excl + v.x + v.y; o.w = excl + v.x + v.y + v.z;
    *(int4*)&p[t * 4] = o;
    if (t == 255) bktCnt[b] = excl + s;
}

// Pass 2b: scan bucket totals -> bucket edge bases (== CSR col bases, bucket order == slot order).
__global__ __launch_bounds__(512) void scans2_k(const int* __restrict__ bktCnt, int* __restrict__ bktEdgeBase) {
    int t = threadIdx.x;
    int v = (t < NBUK) ? bktCnt[t] : 0;
    int lane = t & 63, w = t >> 6;
    __shared__ int wt[8];
    int incl = v;
    #pragma unroll
    for (int d = 1; d < 64; d <<= 1) { int o = __shfl_up(incl, d); if (lane >= d) incl += o; }
    if (lane == 63) wt[w] = incl;
    __syncthreads();
    int wb = 0;
    for (int i = 0; i < w; i++) wb += wt[i];
    int excl = incl - v + wb;
    if (t < NBUK) bktEdgeBase[t] = excl;
    if (t == NBUK - 1) bktEdgeBase[NBUK] = excl + v;
}

// Pass 3: scatter records into each block's private, contiguous per-bucket segments.
// Segments are sequential -> lines fill inside one XCD's L2 -> merged writebacks.
__global__ __launch_bounds__(256) void scatter_k(EdgeArgs a, const int* __restrict__ blkHist,
        const int* __restrict__ bktEdgeBase, unsigned* __restrict__ pool) {
    __shared__ int cur[NBUK];
    int t = threadIdx.x;
    for (int i = t; i < NBUK; i += 256)
        cur[i] = bktEdgeBase[i] + blkHist[(size_t)i * NBLK + blockIdx.x];
    __syncthreads();
    const int per = (TOTE + NBLK - 1) / NBLK;
    int s = blockIdx.x * per;
    int eEnd = min(s + per, TOTE);
    for (int g = s + t; g < eEnd; g += 256) {
        int e = 0;
        while (g >= c_EPRE[e + 1]) e++;
        int k = g - c_EPRE[e];
        int src = a.ei[e][k];
        int dst = a.ei[e][c_ECNT[e] + k];
        int sh = c_BSH[e];
        unsigned rec = ((unsigned)(dst & ((1 << sh) - 1)) << 18) | (unsigned)(c_SRCOFF[e] + src);
        int p = atomicAdd(&cur[c_BBASE[e] + (dst >> sh)], 1);
        pool[p] = rec;
    }
}

// Pass 4: one block per bucket. Records are contiguous [bktEdgeBase[b], bktEdgeBase[b+1]).
// LDS histogram+scan over <=2048 slots; dense CSR writes; col scatter within the bucket's
// contiguous ~55KB range (single-XCD L2 resident -> merged writebacks).
__global__ __launch_bounds__(256) void csrfill_k(
        const unsigned* __restrict__ pool, const int* __restrict__ bktEdgeBase,
        int* __restrict__ cnt, int* __restrict__ cursor, float* __restrict__ invdeg,
        int* __restrict__ col) {
    __shared__ int hist[2048];
    __shared__ int cur[2048];
    __shared__ int wtot[4];
    __shared__ int wbase[4];
    int b = blockIdx.x;
    int t = threadIdx.x;
    int e = 0;
    while (b >= c_BBASE[e + 1]) e++;
    int lb = b - c_BBASE[e];
    int sh = c_BSH[e];
    int s0t = lb << sh;
    int span = min(1 << sh, c_CNTN[e] - s0t);
    int gs0 = c_CNTOFF[e] + s0t;
    int ebase = bktEdgeBase[b];
    int nrec = bktEdgeBase[b + 1] - ebase;

    for (int i = t; i < span; i += 256) hist[i] = 0;
    __syncthreads();
    for (int i = t; i < nrec; i += 256) atomicAdd(&hist[pool[ebase + i] >> 18], 1);
    __syncthreads();
    // exclusive scan over span, 8 elems/thread
    int base = t * 8, loc = 0, lv[8];
    #pragma unroll
    for (int i = 0; i < 8; i++) {
        int ii = base + i;
        int v = (ii < span) ? hist[ii] : 0;
        lv[i] = loc; loc += v;
    }
    int lane = t & 63, w = t >> 6;
    int incl = loc;
    #pragma unroll
    for (int d = 1; d < 64; d <<= 1) { int o = __shfl_up(incl, d); if (lane >= d) incl += o; }
    if (lane == 63) wtot[w] = incl;
    __syncthreads();
    if (t == 0) { int s2 = 0; for (int i = 0; i < 4; i++) { wbase[i] = s2; s2 += wtot[i]; } }
    __syncthreads();
    int texcl = incl - loc + wbase[w];
    #pragma unroll
    for (int i = 0; i < 8; i++) {
        int ii = base + i;
        if (ii < span) cur[ii] = texcl + lv[i];
    }
    __syncthreads();
    // per-slot CSR outputs (dense, coalesced)
    for (int i = t; i < span; i += 256) {
        int c = hist[i];
        cnt[gs0 + i] = c;
        cursor[gs0 + i] = ebase + cur[i] + c;     // end semantics (matches agg_k)
        invdeg[gs0 + i] = 1.0f / fmaxf((float)c, 1.0f);
    }
    __syncthreads();
    // scatter src ids within this bucket's contiguous col range
    for (int i = t; i < nrec; i += 256) {
        unsigned rec = pool[ebase + i];
        int p = atomicAdd(&cur[rec >> 18], 1);
        col[ebase + p] = (int)(rec & 0x3FFFFu);
    }
}

// ---------------- conversions ----------------
struct XArgs { const float* x[7]; };
__global__ __launch_bounds__(256) void convx_k(XArgs a, unsigned short* __restrict__ hbf) {
    int i4 = blockIdx.x * 256 + threadIdx.x;
    if (i4 >= TOTN * 32) return;           // float4 index
    int idx = i4 * 4;
    int t = 0;
    while (idx >= c_NODEPRE[t + 1] * 128) t++;
    float4 v = *(const float4*)&a.x[t][idx - c_NODEPRE[t] * 128];
    uint2 p;
    p.x = (unsigned)f2bf(v.x) | ((unsigned)f2bf(v.y) << 16);
    p.y = (unsigned)f2bf(v.z) | ((unsigned)f2bf(v.w) << 16);
    *(uint2*)&hbf[idx] = p;
}

// weight slots: 0-6 Wp, 7-48 Wl(l*14+e), 49-90 Wr, 91 Wu, 92 Wv  (93 * 16384 elements)
struct WArgs { const float* Wp; const float* Wl; const float* Wr; const float* Wu; const float* Wv; };
__global__ __launch_bounds__(256) void convw_k(WArgs a, unsigned short* __restrict__ wbf) {
    int i4 = blockIdx.x * 256 + threadIdx.x;
    if (i4 >= 93 * 4096) return;
    int idx = i4 * 4;
    int m = idx >> 14;
    int i = idx & 16383;
    const float* src;
    if (m < 7)       src = a.Wp + (size_t)m * 16384;
    else if (m < 49) src = a.Wl + (size_t)(m - 7) * 16384;
    else if (m < 91) src = a.Wr + (size_t)(m - 49) * 16384;
    else if (m == 91) src = a.Wu;
    else              src = a.Wv;
    float4 v = *(const float4*)&src[i];
    uint2 p;
    p.x = (unsigned)f2bf(v.x) | ((unsigned)f2bf(v.y) << 16);
    p.y = (unsigned)f2bf(v.z) | ((unsigned)f2bf(v.w) << 16);
    *(uint2*)&wbf[idx] = p;
}

// ---------------- aggregation: one wave per slot, quarter-wave per neighbor ----------------
#define ACC8(u) do { \
    v[0] += __uint_as_float((u).x << 16); v[1] += __uint_as_float((u).x & 0xFFFF0000u); \
    v[2] += __uint_as_float((u).y << 16); v[3] += __uint_as_float((u).y & 0xFFFF0000u); \
    v[4] += __uint_as_float((u).z << 16); v[5] += __uint_as_float((u).z & 0xFFFF0000u); \
    v[6] += __uint_as_float((u).w << 16); v[7] += __uint_as_float((u).w & 0xFFFF0000u); } while (0)

__global__ __launch_bounds__(256) void agg_k(
        const int* __restrict__ cnt, const int* __restrict__ cursor,
        const float* __restrict__ inv_deg, const int* __restrict__ col,
        const unsigned short* __restrict__ hbf, unsigned short* __restrict__ slotb) {
    int row = blockIdx.x * 4 + (threadIdx.x >> 6);
    if (row >= TOTC) return;
    int lane = threadIdx.x & 63;
    int q = lane >> 4, li = lane & 15;
    int nn = cnt[row];
    int rs = cursor[row] - nn;           // cursor==end
    const int* cp = col + rs;
    float v[8];
    #pragma unroll
    for (int i = 0; i < 8; i++) v[i] = 0.f;
    int j = 0;
    for (; j + 8 <= nn; j += 8) {
        int c0 = cp[j + q] << 7;
        int c1 = cp[j + 4 + q] << 7;
        uint4 u0 = *(const uint4*)&hbf[c0 + li * 8];
        uint4 u1 = *(const uint4*)&hbf[c1 + li * 8];
        ACC8(u0);
        ACC8(u1);
    }
    for (; j < nn; j += 4) {
        if (j + q < nn) {
            int c = cp[j + q] << 7;
            uint4 u = *(const uint4*)&hbf[c + li * 8];
            ACC8(u);
        }
    }
    float inv = inv_deg[row];
    #pragma unroll
    for (int i = 0; i < 8; i++) {
        v[i] += __shfl_xor(v[i], 16);
        v[i] += __shfl_xor(v[i], 32);
        v[i] *= inv;
    }
    if (q == 0) {
        uint4 o;
        o.x = (unsigned)f2bf(v[0]) | ((unsigned)f2bf(v[1]) << 16);
        o.y = (unsigned)f2bf(v[2]) | ((unsigned)f2bf(v[3]) << 16);
        o.z = (unsigned)f2bf(v[4]) | ((unsigned)f2bf(v[5]) << 16);
        o.w = (unsigned)f2bf(v[6]) | ((unsigned)f2bf(v[7]) << 16);
        *(uint4*)&slotb[(size_t)row * HID + li * 8] = o;
    }
}

// ---------------- MFMA GEMM: out = A1@W1^T (+ A2@W2^T) + bias [, l2norm] ----------------
struct GemmArgs {
    int blockPrefix[15];
    const unsigned short* A1[14]; const unsigned short* A2[14];
    const unsigned short* W1[14]; const unsigned short* W2[14];
    const float* bias[14]; void* out[14];
    int rows[14];
};

template<int MODE, bool TWO>
__global__ __launch_bounds__(256) void gemm_k(GemmArgs g) {
    __shared__ short As[64 * 40];
    __shared__ short Ws[128 * 40];
    int b = blockIdx.x;
    int s = 0;
    while (b >= g.blockPrefix[s + 1]) s++;
    int rows = g.rows[s];
    int row0 = (b - g.blockPrefix[s]) * 64;
    int t = threadIdx.x;
    int w = t >> 6, lane = t & 63;
    int q = lane >> 4, m15 = lane & 15;

    floatx4 acc[8];
    #pragma unroll
    for (int bb = 0; bb < 8; bb++) acc[bb] = (floatx4){0.f, 0.f, 0.f, 0.f};

    const int MM = TWO ? 2 : 1;
    for (int mm = 0; mm < MM; mm++) {
        const uint4* A4 = (const uint4*)(mm ? g.A2[s] : g.A1[s]);
        const uint4* W4 = (const uint4*)(mm ? g.W2[s] : g.W1[s]);
        for (int k0 = 0; k0 < 128; k0 += 32) {
            __syncthreads();
            {   // A tile
                int row = t >> 2, kc = t & 3;
                uint4 v = make_uint4(0u, 0u, 0u, 0u);
                if (row0 + row < rows) v = A4[(size_t)(row0 + row) * 16 + (k0 >> 3) + kc];
                *(uint4*)&As[row * 40 + kc * 8] = v;
            }
            #pragma unroll
            for (int i = 0; i < 2; i++) {   // W tile
                int idx = t + i * 256;
                int c = idx >> 2, kc = idx & 3;
                uint4 v = W4[(size_t)c * 16 + (k0 >> 3) + kc];
                *(uint4*)&Ws[c * 40 + kc * 8] = v;
            }
            __syncthreads();
            bf16x8 af = __builtin_bit_cast(bf16x8, *(const short8*)&As[(w * 16 + m15) * 40 + q * 8]);
            #pragma unroll
            for (int bb = 0; bb < 8; bb++) {
                bf16x8 bf = __builtin_bit_cast(bf16x8, *(const short8*)&Ws[(bb * 16 + m15) * 40 + q * 8]);
                acc[bb] = __builtin_amdgcn_mfma_f32_16x16x32_bf16(af, bf, acc[bb], 0, 0, 0);
            }
        }
    }

    const float* bias = g.bias[s];
    #pragma unroll
    for (int bb = 0; bb < 8; bb++) {
        float bv = bias[bb * 16 + m15];
        #pragma unroll
        for (int reg = 0; reg < 4; reg++) acc[bb][reg] += bv;
    }
    if (MODE != 0) {
        #pragma unroll
        for (int reg = 0; reg < 4; reg++) {
            float ss = 0.f;
            #pragma unroll
            for (int bb = 0; bb < 8; bb++) ss += acc[bb][reg] * acc[bb][reg];
            ss += __shfl_xor(ss, 1);
            ss += __shfl_xor(ss, 2);
            ss += __shfl_xor(ss, 4);
            ss += __shfl_xor(ss, 8);
            float sc = 1.0f / fmaxf(sqrtf(ss), 1e-12f);
            #pragma unroll
            for (int bb = 0; bb < 8; bb++) acc[bb][reg] *= sc;
        }
    }
    int rbase = row0 + w * 16 + q * 4;
    if (MODE == 3) {
        float* out = (float*)g.out[s];
        #pragma unroll
        for (int reg = 0; reg < 4; reg++) {
            int r = rbase + reg;
            if (r < rows) {
                float* o = out + (size_t)r * HID;
                #pragma unroll
                for (int bb = 0; bb < 8; bb++) o[bb * 16 + m15] = acc[bb][reg];
            }
        }
    } else {
        unsigned short* out = (unsigned short*)g.out[s];
        #pragma unroll
        for (int reg = 0; reg < 4; reg++) {
            int r = rbase + reg;
            if (r < rows) {
                unsigned short* o = out + (size_t)r * HID;
                #pragma unroll
                for (int bb = 0; bb < 8; bb++)
                    o[bb * 16 + m15] = (MODE == 0) ? f2bf(acc[bb][reg]) : f2h(acc[bb][reg]);
            }
        }
    }
}

// ---------------- per-layer update ----------------
__global__ __launch_bounds__(256) void update_k(unsigned short* __restrict__ hbf,
                                                const unsigned short* __restrict__ slotb,
                                                const float* __restrict__ ln_g, const float* __restrict__ ln_b, int l) {
    int row = blockIdx.x * 4 + (threadIdx.x >> 6);
    if (row >= TOTN) return;
    int lane = threadIdx.x & 63;
    int t = 0;
    while (row >= c_NODEPRE[t + 1]) t++;
    int r = row - c_NODEPRE[t];
    int ns = c_UPD_NS[t];
    float s0 = 0.f, s1 = 0.f;
    for (int s = 0; s < ns; s++) {
        const unsigned short* sp = slotb + (size_t)(c_UPD_BASE[t][s] + r) * HID;
        s0 += h2f(sp[lane]);
        s1 += h2f(sp[lane + 64]);
    }
    float invnd = c_INVND[t];
    const float* gg = ln_g + ((size_t)l * 7 + t) * HID;
    const float* bb = ln_b + ((size_t)l * 7 + t) * HID;
    unsigned short* hp = hbf + (size_t)row * HID;
    float x0 = s0 * invnd + bf2f(hp[lane]);
    float x1 = s1 * invnd + bf2f(hp[lane + 64]);
    float s = x0 + x1;
    s += __shfl_xor(s, 1);  s += __shfl_xor(s, 2);  s += __shfl_xor(s, 4);
    s += __shfl_xor(s, 8);  s += __shfl_xor(s, 16); s += __shfl_xor(s, 32);
    float mean = s * (1.0f / 128.0f);
    float d0 = x0 - mean, d1 = x1 - mean;
    float vs = d0 * d0 + d1 * d1;
    vs += __shfl_xor(vs, 1);  vs += __shfl_xor(vs, 2);  vs += __shfl_xor(vs, 4);
    vs += __shfl_xor(vs, 8);  vs += __shfl_xor(vs, 16); vs += __shfl_xor(vs, 32);
    float rstd = rsqrtf(vs * (1.0f / 128.0f) + 1e-5f);
    float y0 = d0 * rstd * gg[lane]      + bb[lane];
    float y1 = d1 * rstd * gg[lane + 64] + bb[lane + 64];
    hp[lane]      = f2bf(fmaxf(y0, 0.f));
    hp[lane + 64] = f2bf(fmaxf(y1, 0.f));
}

// ---------------- host ----------------
extern "C" void kernel_launch(void* const* d_in, const int* in_sizes, int n_in,
                              void* d_out, int out_size, void* d_ws, size_t ws_size,
                              hipStream_t stream) {
    (void)in_sizes; (void)n_in; (void)out_size; (void)ws_size;
    const float* Wp   = (const float*)d_in[21];
    const float* bp   = (const float*)d_in[22];
    const float* Wl   = (const float*)d_in[23];
    const float* bl   = (const float*)d_in[24];
    const float* Wr   = (const float*)d_in[25];
    const float* ln_g = (const float*)d_in[26];
    const float* ln_b = (const float*)d_in[27];
    const float* Wu   = (const float*)d_in[28];
    const float* bu   = (const float*)d_in[29];
    const float* Wv   = (const float*)d_in[30];
    const float* bv   = (const float*)d_in[31];
    float* out = (float*)d_out;

    // d_ws carve (~224.4 MB)
    unsigned short* h_bf   = (unsigned short*)d_ws;                  // TOTN*128 bf16
    unsigned short* w_bf   = h_bf + (size_t)TOTN * HID;              // 93*16384 bf16
    unsigned short* slotb  = w_bf + (size_t)93 * 16384;              // TOTC*128 bf16/f16
    int*            cnt    = (int*)(slotb + (size_t)TOTC * HID);     // TOTC
    int*            cursor = cnt + TOTC;                             // TOTC
    float*          invdeg = (float*)(cursor + TOTC);                // TOTC
    unsigned*       pool   = (unsigned*)(invdeg + TOTC);             // TOTE records
    int*            blkHist = (int*)(pool + (size_t)TOTE);           // NBUK*NBLK
    int*            ctrl    = blkHist + (size_t)NBUK * NBLK;         // control block
    int* bktCnt       = ctrl;                 // NBUK
    int* bktEdgeBase  = ctrl + NBUK;          // NBUK+1

    // d_out scratch (overwritten by final head GEMM)
    int* col = (int*)d_out;                                          // TOTE ints

    static const int CNTOFF[14] = {0,40000,140000,143000,183000,203000,243000,263000,303000,311000,351000,411000,451000,454000};
    static const int CNTN[14]   = {40000,100000,3000,40000,20000,40000,20000,40000,8000,40000,60000,40000,3000,60000};
    static const int DSTOFF[14] = {100000,0,140000,100000,143000,100000,143000,100000,163000,100000,171000,100000,231000,171000};
    static const int NODEPRE[8] = {0,100000,140000,143000,163000,171000,231000,234000};
    static const int NT[7]      = {100000,40000,3000,20000,8000,60000,3000};

    EdgeArgs ea;
    for (int e = 0; e < 14; e++) ea.ei[e] = (const int*)d_in[7 + e];

    // CSR build: histogram -> scans -> scatter -> per-bucket fill (no global atomics, no memset)
    hist_k<<<NBLK, 256, 0, stream>>>(ea, blkHist);
    scan_blk_k<<<NBUK, 256, 0, stream>>>(blkHist, bktCnt);
    scans2_k<<<1, 512, 0, stream>>>(bktCnt, bktEdgeBase);
    scatter_k<<<NBLK, 256, 0, stream>>>(ea, blkHist, bktEdgeBase, pool);
    csrfill_k<<<NBUK, 256, 0, stream>>>(pool, bktEdgeBase, cnt, cursor, invdeg, col);

    {   // conversions
        XArgs xa;
        for (int t = 0; t < 7; t++) xa.x[t] = (const float*)d_in[t];
        convx_k<<<(TOTN * 32 + 255) / 256, 256, 0, stream>>>(xa, h_bf);
        WArgs wa = {Wp, Wl, Wr, Wu, Wv};
        convw_k<<<(93 * 4096 + 255) / 256, 256, 0, stream>>>(wa, w_bf);
    }

    // input projection (in-place bf16): h_bf[t] = x_bf[t] @ Wp[t]^T + bp[t]
    {
        GemmArgs ga;
        int pre = 0; ga.blockPrefix[0] = 0;
        for (int t = 0; t < 7; t++) {
            ga.A1[t] = h_bf + (size_t)NODEPRE[t] * HID;
            ga.A2[t] = nullptr;
            ga.W1[t] = w_bf + (size_t)t * 16384;
            ga.W2[t] = nullptr;
            ga.bias[t] = bp + (size_t)t * HID;
            ga.out[t] = h_bf + (size_t)NODEPRE[t] * HID;
            ga.rows[t] = NT[t];
            pre += (NT[t] + 63) / 64;
            ga.blockPrefix[t + 1] = pre;
        }
        for (int s = 7; s < 14; s++) { ga.blockPrefix[s + 1] = pre; ga.rows[s] = 0; }
        gemm_k<0, false><<<pre, 256, 0, stream>>>(ga);
    }

    // layers: one agg + one gemm + one update dispatch each
    int ggrid;
    GemmArgs gl;
    {
        int pre = 0; gl.blockPrefix[0] = 0;
        for (int e = 0; e < 14; e++) {
            gl.rows[e] = CNTN[e];
            pre += (CNTN[e] + 63) / 64;
            gl.blockPrefix[e + 1] = pre;
        }
        ggrid = pre;
    }
    for (int l = 0; l < 3; l++) {
        agg_k<<<(TOTC + 3) / 4, 256, 0, stream>>>(cnt, cursor, invdeg, col, h_bf, slotb);
        for (int e = 0; e < 14; e++) {
            gl.A1[e]   = slotb + (size_t)CNTOFF[e] * HID;
            gl.A2[e]   = h_bf + (size_t)DSTOFF[e] * HID;
            gl.W1[e]   = w_bf + (size_t)(7  + l * 14 + e) * 16384;
            gl.W2[e]   = w_bf + (size_t)(49 + l * 14 + e) * 16384;
            gl.bias[e] = bl + ((size_t)l * 14 + e) * HID;
            gl.out[e]  = slotb + (size_t)CNTOFF[e] * HID;   // in-place: bf16 in, f16 out
        }
        gemm_k<1, true><<<ggrid, 256, 0, stream>>>(gl);
        update_k<<<(TOTN + 3) / 4, 256, 0, stream>>>(h_bf, slotb, ln_g, ln_b, l);
    }

    // heads: l2norm(h @ W^T + b) -> fp32 out (overwrites the col scratch in d_out)
    {
        GemmArgs ga;
        ga.blockPrefix[0] = 0;
        ga.A1[0] = h_bf;                        ga.A2[0] = nullptr;
        ga.W1[0] = w_bf + (size_t)91 * 16384;   ga.W2[0] = nullptr;
        ga.bias[0] = bu;                        ga.out[0] = out;
        ga.rows[0] = 100000;
        ga.blockPrefix[1] = (100000 + 63) / 64;
        ga.A1[1] = h_bf + (size_t)100000 * HID; ga.A2[1] = nullptr;
        ga.W1[1] = w_bf + (size_t)92 * 16384;   ga.W2[1] = nullptr;
        ga.bias[1] = bv;                        ga.out[1] = out + (size_t)100000 * HID;
        ga.rows[1] = 40000;
        int tot = ga.blockPrefix[1] + (40000 + 63) / 64;
        for (int s = 2; s < 14; s++) { ga.blockPrefix[s + 1] = tot; ga.rows[s] = 0; }
        ga.blockPrefix[2] = tot;
        gemm_k<3, false><<<tot, 256, 0, stream>>>(ga);
    }
}